// Round 7
// baseline (174.819 us; speedup 1.0000x reference)
//
#include <hip/hip_runtime.h>
#include <math.h>

// MultiBoxLoss (SSD) on MI355X.
// R7: 4 dispatches, no materialized key array.
//   k_main: conf/anchors/loc -> pos losses + 8-bit hist1 (per-slice plain
//           writes, no atomics) + zeros g2/cnum for later kernels.
//   k_h2c: recompute keys (conf is LLC-resident), pick1 per block, 12-bit
//          hist2 of boundary-bin keys, stream-compact keys with top8>=bin1
//          into per-row cbuf (block scan + 1 atomic/block).
//   k_nf:  one block/row: pick2(g2) -> LDS hist3(11b) over compact list ->
//          pick3 -> selection + per-row results (plain stores).
//   k_final: sums slices/rows, writes 8 outputs.
// Lessons applied: no grid.sync (~100us each, R5); no same-address global
// atomic storms (R2); no low-occupancy full-A scans (R1).

#define MAXB 64
#define BPR 16    // blocks per row = A/4096
#define APB 4096  // anchors per block
#define KPT 16    // keys per thread
#define NB2 4096  // key bits [22:11]
#define NB3 2048  // key bits [10:0]

struct Accum {
  int pnp[MAXB * BPR];   // per-slice positive counts (plain writes)
  int ppc[MAXB * BPR];   // per-slice pos-correct
  float pf_loc[MAXB * BPR];
  float pf_clsp[MAXB * BPR];
  float pf_perr[MAXB * BPR];
  float pf_se0[MAXB * BPR];
  float pf_se1[MAXB * BPR];
  int cnum[MAXB];  // compact counts (atomic; zeroed by k_main)
  int b1[MAXB];    // pick1 bin
  int kr1[MAXB];   // pick1 residual rank
  float row_cls[MAXB];
  int row_ntot[MAXB];
  int row_ncor[MAXB];
};

__device__ __forceinline__ float iou_f(float4 g, float4 an) {
  float ax0 = an.x - an.z * 0.5f, ay0 = an.y - an.w * 0.5f;
  float ax1 = an.x + an.z * 0.5f, ay1 = an.y + an.w * 0.5f;
  float ltx = fmaxf(g.x, ax0), lty = fmaxf(g.y, ay0);
  float rbx = fminf(g.z, ax1), rby = fminf(g.w, ay1);
  float w = fmaxf(rbx - ltx, 0.f), h = fmaxf(rby - lty, 0.f);
  float inter = w * h;
  float area_g = (g.z - g.x) * (g.w - g.y);
  float area_a = (ax1 - ax0) * (ay1 - ay0);
  return inter / (area_g + area_a - inter);
}

__device__ __forceinline__ float sl1(float x) {
  float ax = fabsf(x);
  return ax < 1.f ? 0.5f * x * x : ax - 0.5f;
}

// pick over the 256-bin level-1 histogram stored as BPR per-slice slabs.
__device__ uint2 pick_l1(const unsigned int* __restrict__ g1, int b, int kr_in,
                         unsigned int* s_ws, volatile unsigned int* s_bin,
                         volatile unsigned int* s_kr) {
  int tid = threadIdx.x, lane = tid & 63, wv = tid >> 6;
  const unsigned int* base = g1 + b * BPR * 256;
  unsigned int my = 0;
#pragma unroll
  for (int s = 0; s < BPR; ++s) my += base[s * 256 + tid];
  unsigned int v = my;
#pragma unroll
  for (int o = 1; o < 64; o <<= 1) {
    unsigned int t = __shfl_down(v, o, 64);
    if (lane + o < 64) v += t;
  }
  if (lane == 0) s_ws[wv] = v;
  __syncthreads();
  unsigned int off = 0;
  for (int w2 = wv + 1; w2 < 4; ++w2) off += s_ws[w2];
  unsigned int incl = v + off, above = incl - my;
  if ((int)above < kr_in && kr_in <= (int)incl) {
    *s_bin = (unsigned int)tid;
    *s_kr = (unsigned int)(kr_in - (int)above);
  }
  __syncthreads();
  uint2 r;
  r.x = *s_bin;
  r.y = *s_kr;
  __syncthreads();
  return r;
}

// generic pick over an NB-bin histogram (global or LDS pointer).
template <int NB>
__device__ uint2 pick_hist(const unsigned int* __restrict__ h, int kr_in,
                           unsigned int* s_ws, volatile unsigned int* s_bin,
                           volatile unsigned int* s_kr) {
  int tid = threadIdx.x, lane = tid & 63, wv = tid >> 6;
  constexpr int PER = NB / 256;
  unsigned int loc[PER];
  unsigned int my = 0;
#pragma unroll
  for (int i = 0; i < PER; ++i) {
    loc[i] = h[tid * PER + i];
    my += loc[i];
  }
  unsigned int v = my;
#pragma unroll
  for (int o = 1; o < 64; o <<= 1) {
    unsigned int t = __shfl_down(v, o, 64);
    if (lane + o < 64) v += t;
  }
  if (lane == 0) s_ws[wv] = v;
  __syncthreads();
  unsigned int off = 0;
  for (int w2 = wv + 1; w2 < 4; ++w2) off += s_ws[w2];
  unsigned int incl = v + off, above = incl - my;
  if ((int)above < kr_in && kr_in <= (int)incl) {
    int kk = kr_in - (int)above;
#pragma unroll
    for (int i = PER - 1; i >= 0; --i) {
      int c = (int)loc[i];
      if (kk <= c) {
        *s_bin = (unsigned int)(tid * PER + i);
        *s_kr = (unsigned int)kk;
        break;
      }
      kk -= c;
    }
  }
  __syncthreads();
  uint2 r;
  r.x = *s_bin;
  r.y = *s_kr;
  __syncthreads();
  return r;
}

// Pass 1: positive losses + 8-bit hist1; also zeros g2/cnum for later passes.
__global__ __launch_bounds__(256) void k_main(
    const float* __restrict__ loc_pred, const float* __restrict__ conf,
    const float* __restrict__ gt, const float* __restrict__ anchors,
    Accum* __restrict__ acc, unsigned int* __restrict__ g1,
    unsigned int* __restrict__ g2, int A) {
  int sl = blockIdx.x, b = blockIdx.y;
  int linear = b * BPR + sl;
  int tid = threadIdx.x, lane = tid & 63, wv = tid >> 6;
  __shared__ unsigned int hist[4][256];
  __shared__ float smf[5][4];
  __shared__ int smi[2][4];
  // zero scratch used by later kernels (plain stores; kernel boundary
  // makes them visible)
  g2[linear * 256 + tid] = 0u;  // 1024 blocks x 256 = 64*4096 exactly
  if (linear == 0 && tid < MAXB) acc->cnum[tid] = 0;
  for (int i = tid; i < 1024; i += 256) ((unsigned int*)hist)[i] = 0u;
  __syncthreads();

  float4 g4 = reinterpret_cast<const float4*>(gt)[b];
  const float4* conf4 = reinterpret_cast<const float4*>(conf);
  const float4* anc4 = reinterpret_cast<const float4*>(anchors);
  const float4* loc4 = reinterpret_cast<const float4*>(loc_pred);
  int abase = sl * APB;
  long long cbase = ((long long)b * A + abase) >> 1;  // float4 units

  float loc_s = 0.f, clsp = 0.f, perr = 0.f, se0 = 0.f, se1 = 0.f;
  int pcnt = 0, pcor = 0;

#pragma unroll
  for (int j = 0; j < 8; ++j) {
    float4 cc = conf4[cbase + tid + j * 256];
    int a0 = abase + 2 * (tid + j * 256);
#pragma unroll
    for (int h = 0; h < 2; ++h) {
      int a = a0 + h;
      float c0 = h ? cc.z : cc.x;
      float c1 = h ? cc.w : cc.y;
      float4 an = anc4[a];
      float ov = iou_f(g4, an);
      unsigned int kk = 0u;
      if (ov <= 0.3f) {
        float m = fmaxf(c0, c1);
        float s = logf(expf(c0 - m) + expf(c1 - m));
        kk = __float_as_uint((m - c0) + s);
      }
      atomicAdd(&hist[wv][kk >> 23], 1u);  // kk has no sign bit here
      if (ov >= 0.6f) {
        float4 lp = loc4[(long long)b * A + a];
        float gcx = (g4.x + g4.z) * 0.5f, gcy = (g4.y + g4.w) * 0.5f;
        float gw = g4.z - g4.x, gh = g4.w - g4.y;
        float t0 = (gcx - an.x) / (0.1f * an.z);
        float t1 = (gcy - an.y) / (0.1f * an.w);
        float t2 = logf(gw / an.z) / 0.2f;
        float t3 = logf(gh / an.w) / 0.2f;
        loc_s += sl1(lp.x - t0) + sl1(lp.y - t1) + sl1(lp.z - t2) +
                 sl1(lp.w - t3);
        float m = fmaxf(c0, c1);
        float s = logf(expf(c0 - m) + expf(c1 - m));
        clsp += (m - c1) + s;
        pcnt += 1;
        pcor += (c1 > c0) ? 1 : 0;
        float dcx = an.x + lp.x * 0.1f * an.z;
        float dcy = an.y + lp.y * 0.1f * an.w;
        float dw = an.z * expf(lp.z * 0.2f);
        float dh = an.w * expf(lp.w * 0.2f);
        float dx0 = dcx - dw * 0.5f, dy0 = dcy - dh * 0.5f;
        float ex = (g4.x - dx0) * 255.f, ey = (g4.y - dy0) * 255.f;
        perr += sqrtf(ex * ex + ey * ey);
        se0 += fabsf(g4.z - (dx0 + dw));
        se1 += fabsf(g4.w - (dy0 + dh));
      }
    }
  }

  // flush hist1 slice (plain store, unconditional)
  __syncthreads();
  g1[linear * 256 + tid] =
      hist[0][tid] + hist[1][tid] + hist[2][tid] + hist[3][tid];

  // block totals -> per-slice plain stores (no atomics, no pre-zero)
  float fv[5] = {loc_s, clsp, perr, se0, se1};
  int iv[2] = {pcnt, pcor};
#pragma unroll
  for (int q = 0; q < 5; ++q) {
    float v = fv[q];
#pragma unroll
    for (int o = 32; o > 0; o >>= 1) v += __shfl_down(v, o, 64);
    if (lane == 0) smf[q][wv] = v;
  }
#pragma unroll
  for (int q = 0; q < 2; ++q) {
    int v = iv[q];
#pragma unroll
    for (int o = 32; o > 0; o >>= 1) v += __shfl_down(v, o, 64);
    if (lane == 0) smi[q][wv] = v;
  }
  __syncthreads();
  if (tid == 0) {
    float L = 0, C = 0, P = 0, S0 = 0, S1 = 0;
    int PC = 0, COR = 0;
    for (int w2 = 0; w2 < 4; ++w2) {
      L += smf[0][w2]; C += smf[1][w2]; P += smf[2][w2];
      S0 += smf[3][w2]; S1 += smf[4][w2];
      PC += smi[0][w2]; COR += smi[1][w2];
    }
    acc->pnp[linear] = PC;
    acc->ppc[linear] = COR;
    acc->pf_loc[linear] = L;
    acc->pf_clsp[linear] = C;
    acc->pf_perr[linear] = P;
    acc->pf_se0[linear] = S0;
    acc->pf_se1[linear] = S1;
  }
}

// Pass 2: pick1, hist2 of boundary-bin keys, compact top8>=bin1 keys.
__global__ __launch_bounds__(256) void k_h2c(
    const float* __restrict__ conf, const float* __restrict__ gt,
    const float* __restrict__ anchors, Accum* __restrict__ acc,
    const unsigned int* __restrict__ g1, unsigned int* __restrict__ g2,
    unsigned int* __restrict__ cbuf, int A) {
  int sl = blockIdx.x, b = blockIdx.y;
  int tid = threadIdx.x, lane = tid & 63, wv = tid >> 6;
  __shared__ unsigned int s_ws[4];
  __shared__ unsigned int s_bin, s_kr;
  __shared__ unsigned int h2[NB2];  // 16 KB
  __shared__ unsigned int s_base;

  int np = 0;
#pragma unroll
  for (int s = 0; s < BPR; ++s) np += acc->pnp[b * BPR + s];
  int k = 3 * np;
  if (k < 10) k = 10;
  if (k > A - 1) k = A - 1;
  uint2 p1 = pick_l1(g1, b, k, s_ws, &s_bin, &s_kr);
  unsigned int bin1 = p1.x;
  if (sl == 0 && tid == 0) {
    acc->b1[b] = (int)p1.x;
    acc->kr1[b] = (int)p1.y;
  }
  for (int i = tid; i < NB2; i += 256) h2[i] = 0u;
  __syncthreads();

  float4 g4 = reinterpret_cast<const float4*>(gt)[b];
  const float4* conf4 = reinterpret_cast<const float4*>(conf);
  const float4* anc4 = reinterpret_cast<const float4*>(anchors);
  int abase = sl * APB;
  long long cbase = ((long long)b * A + abase) >> 1;

  unsigned int keys[KPT];
  int cnt = 0;
#pragma unroll
  for (int j = 0; j < 8; ++j) {
    float4 cc = conf4[cbase + tid + j * 256];
    int a0 = abase + 2 * (tid + j * 256);
#pragma unroll
    for (int h = 0; h < 2; ++h) {
      float c0 = h ? cc.z : cc.x;
      float c1 = h ? cc.w : cc.y;
      float4 an = anc4[a0 + h];
      float ov = iou_f(g4, an);
      unsigned int kk = 0u;
      if (ov <= 0.3f) {
        float m = fmaxf(c0, c1);
        float s = logf(expf(c0 - m) + expf(c1 - m));
        kk = __float_as_uint((m - c0) + s);
      }
      if (c1 > c0) kk |= 0x80000000u;
      keys[2 * j + h] = kk;
      unsigned int top8 = (kk & 0x7FFFFFFFu) >> 23;
      if (top8 == bin1) atomicAdd(&h2[(kk >> 11) & 0xFFFu], 1u);
      if (top8 >= bin1) ++cnt;
    }
  }
  __syncthreads();
  for (int i = tid; i < NB2; i += 256)
    if (h2[i]) atomicAdd(&g2[b * NB2 + i], h2[i]);

  // stream compaction: block exclusive scan of per-thread counts
  unsigned int v = (unsigned int)cnt;
#pragma unroll
  for (int o = 1; o < 64; o <<= 1) {
    unsigned int t = __shfl_up(v, o, 64);
    if (lane >= o) v += t;
  }
  if (lane == 63) s_ws[wv] = v;
  __syncthreads();
  unsigned int woff = 0;
  for (int w2 = 0; w2 < wv; ++w2) woff += s_ws[w2];
  unsigned int excl = woff + v - (unsigned int)cnt;
  if (tid == 0) {
    unsigned int total = s_ws[0] + s_ws[1] + s_ws[2] + s_ws[3];
    s_base = (unsigned int)atomicAdd(&acc->cnum[b], (int)total);
  }
  __syncthreads();
  unsigned int w = s_base + excl;
  unsigned int* crow = cbuf + (size_t)b * A;
#pragma unroll
  for (int j = 0; j < KPT; ++j) {
    unsigned int kk = keys[j];
    if (((kk & 0x7FFFFFFFu) >> 23) >= bin1) crow[w++] = kk;
  }
}

// Pass 3: one block per row — pick2, hist3, pick3, selection.
__global__ __launch_bounds__(256) void k_nf(const unsigned int* __restrict__ g2,
                                            const unsigned int* __restrict__ cbuf,
                                            Accum* __restrict__ acc, int A) {
  int b = blockIdx.x;
  int tid = threadIdx.x, lane = tid & 63, wv = tid >> 6;
  __shared__ unsigned int s_ws[4];
  __shared__ unsigned int s_bin, s_kr;
  __shared__ unsigned int h3[NB3];  // 8 KB
  __shared__ int s_tie;
  __shared__ float smf[4];
  __shared__ int smi[2][4];

  unsigned int bin1 = (unsigned int)acc->b1[b];
  int kr1 = acc->kr1[b];
  uint2 p2 = pick_hist<NB2>(g2 + b * NB2, kr1, s_ws, &s_bin, &s_kr);
  unsigned int pref20 = (bin1 << 12) | p2.x;
  int cnt = acc->cnum[b];
  for (int i = tid; i < NB3; i += 256) h3[i] = 0u;
  if (tid == 0) s_tie = 0;
  __syncthreads();

  const unsigned int* crow = cbuf + (size_t)b * A;
  for (int i = tid; i < cnt; i += 256) {
    unsigned int k31 = crow[i] & 0x7FFFFFFFu;
    if ((k31 >> 11) == pref20) atomicAdd(&h3[k31 & 0x7FFu], 1u);
  }
  __syncthreads();
  uint2 p3 = pick_hist<NB3>(h3, (int)p2.y, s_ws, &s_bin, &s_kr);
  unsigned int thr = (pref20 << 11) | p3.x;
  int need = (int)p3.y;

  float cls = 0.f;
  int ncnt = 0, ncor = 0;
  for (int i = tid; i < cnt; i += 256) {
    unsigned int kk = crow[i];
    unsigned int k31 = kk & 0x7FFFFFFFu;
    bool s = false;
    if (k31 > thr) {
      s = true;
    } else if (k31 == thr) {
      if (atomicAdd(&s_tie, 1) < need) s = true;
    }
    if (s) {
      cls += __uint_as_float(k31);
      ncnt += 1;
      ncor += (int)((kk >> 31) ^ 1u);
    }
  }
  {
    float v = cls;
#pragma unroll
    for (int o = 32; o > 0; o >>= 1) v += __shfl_down(v, o, 64);
    if (lane == 0) smf[wv] = v;
  }
  {
    int v = ncnt;
#pragma unroll
    for (int o = 32; o > 0; o >>= 1) v += __shfl_down(v, o, 64);
    if (lane == 0) smi[0][wv] = v;
  }
  {
    int v = ncor;
#pragma unroll
    for (int o = 32; o > 0; o >>= 1) v += __shfl_down(v, o, 64);
    if (lane == 0) smi[1][wv] = v;
  }
  __syncthreads();
  if (tid == 0) {
    acc->row_cls[b] = smf[0] + smf[1] + smf[2] + smf[3];
    acc->row_ntot[b] = smi[0][0] + smi[0][1] + smi[0][2] + smi[0][3];
    acc->row_ncor[b] = smi[1][0] + smi[1][1] + smi[1][2] + smi[1][3];
  }
}

__global__ __launch_bounds__(256) void k_final(const Accum* __restrict__ acc,
                                               float* __restrict__ out) {
  __shared__ float sm[256];
  int t = threadIdx.x;
  const int NSL = MAXB * BPR;
  float vals[10];
  float s;
  s = 0; for (int i = t; i < NSL; i += 256) s += acc->pf_loc[i];  vals[0] = s;
  s = 0; for (int i = t; i < NSL; i += 256) s += acc->pf_clsp[i]; vals[1] = s;
  s = 0; for (int i = t; i < NSL; i += 256) s += acc->pf_perr[i]; vals[2] = s;
  s = 0; for (int i = t; i < NSL; i += 256) s += acc->pf_se0[i];  vals[3] = s;
  s = 0; for (int i = t; i < NSL; i += 256) s += acc->pf_se1[i];  vals[4] = s;
  s = 0; for (int i = t; i < MAXB; i += 256) s += acc->row_cls[i]; vals[5] = s;
  s = 0; for (int i = t; i < NSL; i += 256) s += (float)acc->ppc[i]; vals[6] = s;
  s = 0; for (int i = t; i < MAXB; i += 256) s += (float)acc->row_ncor[i]; vals[7] = s;
  s = 0; for (int i = t; i < MAXB; i += 256) s += (float)acc->row_ntot[i]; vals[8] = s;
  s = 0; for (int i = t; i < NSL; i += 256) s += (float)acc->pnp[i]; vals[9] = s;
  float tot[10];
  for (int q = 0; q < 10; ++q) {
    sm[t] = vals[q];
    __syncthreads();
    for (int o = 128; o > 0; o >>= 1) {
      if (t < o) sm[t] += sm[t + o];
      __syncthreads();
    }
    tot[q] = sm[0];
    __syncthreads();
  }
  if (t == 0) {
    float N = tot[9];
    float Nf = fmaxf(N, 1.f);
    out[0] = tot[0] / (Nf * 4.f);
    float wsum = N + tot[8] * (1.f / 3.f);
    out[1] = (tot[1] + tot[5] * (1.f / 3.f)) / wsum;
    out[2] = tot[6] / fmaxf(N, 1.f);
    out[3] = tot[7] / fmaxf(tot[8], 1.f);
    out[4] = tot[2] / Nf;
    out[5] = tot[3] / Nf * 255.f;
    out[6] = tot[4] / Nf * 255.f;
    out[7] = N;
  }
}

extern "C" void kernel_launch(void* const* d_in, const int* in_sizes, int n_in,
                              void* d_out, int out_size, void* d_ws,
                              size_t ws_size, hipStream_t stream) {
  (void)n_in; (void)out_size; (void)ws_size;
  const float* loc = (const float*)d_in[0];
  const float* conf = (const float*)d_in[1];
  const float* gt = (const float*)d_in[2];
  const float* anchors = (const float*)d_in[3];
  int B = in_sizes[2] / 4;  // 64
  int A = in_sizes[3] / 4;  // 65536
  float* out = (float*)d_out;

  char* w = (char*)d_ws;
  Accum* acc = (Accum*)w;
  size_t off = (sizeof(Accum) + 255) & ~(size_t)255;
  unsigned int* g1 = (unsigned int*)(w + off);
  off += (size_t)MAXB * BPR * 256 * 4;
  unsigned int* g2 = (unsigned int*)(w + off);
  off += (size_t)MAXB * NB2 * 4;
  unsigned int* cbuf = (unsigned int*)(w + off);

  dim3 grid(A / APB, B);  // (16, 64)
  k_main<<<grid, 256, 0, stream>>>(loc, conf, gt, anchors, acc, g1, g2, A);
  k_h2c<<<grid, 256, 0, stream>>>(conf, gt, anchors, acc, g1, g2, cbuf, A);
  k_nf<<<B, 256, 0, stream>>>(g2, cbuf, acc, A);
  k_final<<<1, 256, 0, stream>>>(acc, out);
}